// Round 3
// baseline (46.594 us; speedup 1.0000x reference)
//
#include <hip/hip_runtime.h>

// Identity op: out = x (4096*8192 float32). Pure copy.
// Experiment: nontemporal (streaming) stores so the 128 MiB output does NOT
// allocate in L2/L3 — leaves the full 256 MiB Infinity Cache for the input,
// which is re-read every graph replay and can become fully L3-resident.
// Reads stay cached. Target: write-limited floor (~7 TB/s pure-write rate
// observed on fillBufferAligned) instead of mixed-traffic 6.3 TB/s.

__global__ __launch_bounds__(256) void copy_f4_nt(const float4* __restrict__ in,
                                                  float4* __restrict__ out,
                                                  int n4) {
    int stride = gridDim.x * blockDim.x;
    for (int i = blockIdx.x * blockDim.x + threadIdx.x; i < n4; i += stride) {
        float4 v = in[i];  // cached load — let L3 keep the input
        __builtin_nontemporal_store(v.x, &out[i].x);
        __builtin_nontemporal_store(v.y, &out[i].y);
        __builtin_nontemporal_store(v.z, &out[i].z);
        __builtin_nontemporal_store(v.w, &out[i].w);
    }
}

extern "C" void kernel_launch(void* const* d_in, const int* in_sizes, int n_in,
                              void* d_out, int out_size, void* d_ws, size_t ws_size,
                              hipStream_t stream) {
    const float4* x = (const float4*)d_in[0];
    float4* out = (float4*)d_out;
    int n4 = out_size / 4;  // 8388608
    int blocks = 2048;      // 8 blocks/CU, grid-stride covers the rest
    copy_f4_nt<<<blocks, 256, 0, stream>>>(x, out, n4);
}

// Round 4
// 42.018 us; speedup vs baseline: 1.1089x; 1.1089x over previous
//
#include <hip/hip_runtime.h>

// Reference: for i in range(1000): x = 1.0 * x  -> identity.
// Output = input, float32, 4096*8192 elements. Pure D2D copy.
//
// Roofline: 128 MiB read + 128 MiB write per call is mandatory (no aliasing
// d_in/d_out; harness forbids relying on d_out state across replays).
// 268 MB / ~6.3 TB/s achievable mixed-traffic BW ≈ 42 µs.
// Measured: hipMemcpyAsync (SDMA/blit) 42.2 µs = 6.36 TB/s — fastest of
// {memcpy 42.2, cached float4 kernel 45.6, NT-store kernel 46.6}.
// NT stores cut HBM traffic to 201 MB but were SLOWER — the path is
// rate-limited, not fetch-limited. Revert to memcpy.

extern "C" void kernel_launch(void* const* d_in, const int* in_sizes, int n_in,
                              void* d_out, int out_size, void* d_ws, size_t ws_size,
                              hipStream_t stream) {
    const float* x = (const float*)d_in[0];
    float* out = (float*)d_out;
    size_t nbytes = (size_t)out_size * sizeof(float);
    hipMemcpyAsync(out, x, nbytes, hipMemcpyDeviceToDevice, stream);
}